// Round 6
// baseline (774.036 us; speedup 1.0000x reference)
//
#include <hip/hip_runtime.h>
#include <stdint.h>
#include <stddef.h>

// ---------- types ----------
typedef _Float16 half_t;
typedef half_t half8  __attribute__((ext_vector_type(8)));
typedef half_t half4v __attribute__((ext_vector_type(4)));
typedef float  f32x4  __attribute__((ext_vector_type(4)));

__device__ __forceinline__ float fast_sigmoid(float x) {
    float e = __builtin_amdgcn_exp2f(-1.44269504f * x);
    return __builtin_amdgcn_rcpf(1.0f + e);
}
__device__ __forceinline__ float fast_tanh(float x) {
    float e = __builtin_amdgcn_exp2f(2.88539008f * x);
    return 1.0f - 2.0f * __builtin_amdgcn_rcpf(1.0f + e);
}

// ---------------------------------------------------------------------------
// Prep: W [1024][256] f32 row-major -> MFMA-B fragment order, f16.
// Bijection (contiguous k): lane l, elem e of tile (T,kt) holds
//   B[k = kt*32 + (l>>4)*8 + e, j = T*16 + (l&15)].
// A-fragments from LDS use the SAME (lane-group,elem)->k mapping (validated
// R1/R3/R4/R5: absmax 2e-3).
// ---------------------------------------------------------------------------
__global__ __launch_bounds__(64) void shuffle_w_kernel(
    const float* __restrict__ W, half_t* __restrict__ out)
{
    const int blk = blockIdx.x;         // 512 = 64 T * 8 kt
    const int T = blk >> 3, kt = blk & 7;
    const int l = threadIdx.x;
    const int j = T * 16 + (l & 15);
    const int k0 = kt * 32 + ((l >> 4) << 3);
    half8 v;
#pragma unroll
    for (int e = 0; e < 8; ++e) v[e] = (half_t)W[j * 256 + k0 + e];
    *reinterpret_cast<half8*>(out + (size_t)(blk * 64 + l) * 8) = v;
}

// ---------------------------------------------------------------------------
// Single-pass 4-gate GEMM: acc[mt*8 + g*2 + j] += hx(64x256) @ W^T tile
// (g*16 + w*2 + j).  Full unroll, NO sched pins: at 512-thread blocks the
// unified reg budget is 512/wave (2 waves/SIMD), so the scheduler can hoist
// loads freely without forcing spills (R2-R5 failure mode was the 128-reg
// cap of 1024-thread blocks, visible as VGPR_Count=64 all four rounds).
// ---------------------------------------------------------------------------
__device__ __forceinline__ void gemm_all(
    f32x4* acc, const half_t* __restrict__ lhx,
    const half_t* __restrict__ Ws, int w, int lm, int lg, int l)
{
#pragma unroll
    for (int kt = 0; kt < 8; ++kt) {
        half8 a[4];
#pragma unroll
        for (int mt = 0; mt < 4; ++mt) {
            const int p = mt * 16 + lm;
            const int k = (kt * 32 + lg * 8) ^ ((p & 7) << 4);
            a[mt] = *reinterpret_cast<const half8*>(&lhx[p * 256 + k]);
        }
#pragma unroll
        for (int g = 0; g < 4; ++g)
#pragma unroll
            for (int j = 0; j < 2; ++j) {
                const int T = g * 16 + w * 2 + j;
                half8 b = *reinterpret_cast<const half8*>(
                    &Ws[(size_t)((T * 8 + kt) * 64 + l) * 8]);
#pragma unroll
                for (int mt = 0; mt < 4; ++mt)
                    acc[mt * 8 + g * 2 + j] = __builtin_amdgcn_mfma_f32_16x16x32_f16(
                        a[mt], b, acc[mt * 8 + g * 2 + j], 0, 0, 0);
            }
    }
}

// ---------------------------------------------------------------------------
// Persistent LSTM: block = 64 rows x 16 steps, 8 waves (512 threads).
// Wave w owns h-cols [w*32, w*32+32) = tiles g*16 + w*2 + {0,1} per gate.
// ONE pass computes all 4 gates (acc = 32 f32x4 = 128 AGPR); epilogue is
// fully thread-local. 2 waves/SIMD, 512-reg budget -> no spills.
// LDS: hx 32 KB (XOR-swizzled rows) + x_proj frag dump 128 KB = 160 KB.
// ---------------------------------------------------------------------------
__global__ __launch_bounds__(512, 2) void lstm_kernel(
    const float* __restrict__ x,      // [8][256][1600]
    const float* __restrict__ hx0,    // [12800][256]
    const float* __restrict__ cx0,    // [12800][256]
    const float* __restrict__ b_ih,   // [1024]
    const float* __restrict__ b_hh,   // [1024]
    const float* __restrict__ W_lin,  // [2][256]
    const float* __restrict__ b_lin,  // [2]
    const half_t* __restrict__ Wih_s, // shuffled f16
    const half_t* __restrict__ Whh_s, // shuffled f16
    float* __restrict__ out)          // [12800][16][2]
{
    __shared__ __align__(16) half_t lds_hx[64 * 256];        // 32 KB
    __shared__ __align__(16) half_t lds_xp[8 * 32 * 64 * 4]; // 128 KB

    const int tid = threadIdx.x;
    const int w  = tid >> 6;   // wave 0..7
    const int l  = tid & 63;
    const int lm = l & 15;
    const int lg = l >> 4;

    const int row0 = blockIdx.x * 64;     // 200 blocks * 64 rows
    const int bb_  = row0 / 1600;
    const int p0   = row0 % 1600;

    // ---- stage x tile into lds_hx, f16 swizzled (coalesced on p) ----
    {
        const float* xin = x + (size_t)bb_ * 409600 + p0;   // x[b][c][p0+p]
        for (int it = 0; it < 32; ++it) {
            int idx = it * 512 + tid;
            int p = idx & 63, c = idx >> 6;
            lds_hx[p * 256 + (c ^ ((p & 7) << 4))] = (half_t)xin[c * 1600 + p];
        }
    }
    __syncthreads();

    f32x4 acc[32];

    // ---------------- phase 0: x_proj = x @ W_ih^T + b_ih + b_hh ----------
#pragma unroll
    for (int g = 0; g < 4; ++g)
#pragma unroll
        for (int j = 0; j < 2; ++j) {
            int col = g * 256 + (w * 2 + j) * 16 + lm;
            float bias = b_ih[col] + b_hh[col];
#pragma unroll
            for (int mt = 0; mt < 4; ++mt)
                acc[mt * 8 + g * 2 + j] = (f32x4){bias, bias, bias, bias};
        }
    gemm_all(acc, lds_hx, Wih_s, w, lm, lg, l);

    // dump x_proj to own-wave LDS region as f16 (read back identically)
#pragma unroll
    for (int f = 0; f < 32; ++f) {
        half4v xv;
#pragma unroll
        for (int r = 0; r < 4; ++r) xv[r] = (half_t)acc[f][r];
        *reinterpret_cast<half4v*>(&lds_xp[((w * 32 + f) * 64 + l) * 4]) = xv;
    }
    __syncthreads();   // x tile fully consumed, xp written

    // ---- stage h0 into lds_hx (coalesced on c); cx into registers ----
    {
        const float* hin = hx0 + (size_t)row0 * 256;
        for (int it = 0; it < 32; ++it) {
            int idx = it * 512 + tid;
            int c = idx & 255, p = idx >> 8;
            lds_hx[p * 256 + (c ^ ((p & 7) << 4))] = (half_t)hin[p * 256 + c];
        }
    }
    float cxr[32];
#pragma unroll
    for (int mt = 0; mt < 4; ++mt)
#pragma unroll
        for (int j = 0; j < 2; ++j)
#pragma unroll
            for (int r = 0; r < 4; ++r) {
                int p = mt * 16 + lg * 4 + r;
                int c = w * 32 + j * 16 + lm;
                cxr[(mt * 2 + j) * 4 + r] = cx0[(size_t)(row0 + p) * 256 + c];
            }
    __syncthreads();

    // ---------------- 16 recurrent steps ----------------
#pragma unroll 1
    for (int t = 0; t < 16; ++t) {
        // acc init = x_proj (own-wave frag dump)
#pragma unroll
        for (int f = 0; f < 32; ++f) {
            half4v u = *reinterpret_cast<const half4v*>(
                &lds_xp[((w * 32 + f) * 64 + l) * 4]);
#pragma unroll
            for (int r = 0; r < 4; ++r) acc[f][r] = (float)u[r];
        }

        gemm_all(acc, lds_hx, Whh_s, w, lm, lg, l);

        __syncthreads();   // all waves finished reading lds_hx(t)

        // cell update (all 4 gates local); write hx(t+1) f16-swizzled
#pragma unroll
        for (int mt = 0; mt < 4; ++mt)
#pragma unroll
            for (int j = 0; j < 2; ++j)
#pragma unroll
                for (int r = 0; r < 4; ++r) {
                    float iv = acc[mt * 8 + 0 + j][r];
                    float fv = acc[mt * 8 + 2 + j][r];
                    float gv = acc[mt * 8 + 4 + j][r];
                    float ov = acc[mt * 8 + 6 + j][r];
                    float cxn = fast_sigmoid(fv) * cxr[(mt * 2 + j) * 4 + r] +
                                fast_sigmoid(iv) * fast_tanh(gv);
                    cxr[(mt * 2 + j) * 4 + r] = cxn;
                    float h = fast_sigmoid(ov) * fast_tanh(cxn);
                    int p  = mt * 16 + lg * 4 + r;
                    int cc = w * 32 + j * 16 + lm;
                    lds_hx[p * 256 + (cc ^ ((p & 7) << 4))] = (half_t)h;
                }
        __syncthreads();   // hx(t+1) visible to all

        // head: y = leaky_relu(hx) @ W_lin^T + b_lin, write [n][t][o]
        {
            const int p = tid >> 3;          // row 0..63
            const int o = (tid >> 2) & 1;    // output 0..1
            const int q = tid & 3;           // quarter of the 256 h-cols
            const float* wl = W_lin + o * 256;
            float s = 0.0f;
#pragma unroll
            for (int cb = 0; cb < 16; ++cb) {
                int c0 = q * 64 + cb * 4;
                half4v u = *reinterpret_cast<const half4v*>(
                    &lds_hx[p * 256 + (c0 ^ ((p & 7) << 4))]);
                float4 wv = *reinterpret_cast<const float4*>(wl + c0);
                float h0 = (float)u[0], h1 = (float)u[1];
                float h2 = (float)u[2], h3 = (float)u[3];
                s += fmaxf(h0, 0.01f * h0) * wv.x;
                s += fmaxf(h1, 0.01f * h1) * wv.y;
                s += fmaxf(h2, 0.01f * h2) * wv.z;
                s += fmaxf(h3, 0.01f * h3) * wv.w;
            }
            s += __shfl_xor(s, 1);
            s += __shfl_xor(s, 2);
            if (q == 0)
                out[((size_t)(row0 + p) * 16 + t) * 2 + o] = s + b_lin[o];
        }
    }
}

// ---------------------------------------------------------------------------
extern "C" void kernel_launch(void* const* d_in, const int* in_sizes, int n_in,
                              void* d_out, int out_size, void* d_ws, size_t ws_size,
                              hipStream_t stream)
{
    const float* x    = (const float*)d_in[0];
    const float* hx   = (const float*)d_in[1];
    const float* cx   = (const float*)d_in[2];
    const float* Wih  = (const float*)d_in[3];
    const float* Whh  = (const float*)d_in[4];
    const float* bih  = (const float*)d_in[5];
    const float* bhh  = (const float*)d_in[6];
    const float* Wlin = (const float*)d_in[7];
    const float* blin = (const float*)d_in[8];
    float* out = (float*)d_out;

    half_t* wih_s = (half_t*)d_ws;             // 512 KB
    half_t* whh_s = wih_s + 1024 * 256;        // 512 KB

    shuffle_w_kernel<<<512, 64, 0, stream>>>(Wih, wih_s);
    shuffle_w_kernel<<<512, 64, 0, stream>>>(Whh, whh_s);
    lstm_kernel<<<200, 512, 0, stream>>>(x, hx, cx, bih, bhh, Wlin, blin,
                                         wih_s, whh_s, out);
}

// Round 7
// 362.179 us; speedup vs baseline: 2.1372x; 2.1372x over previous
//
#include <hip/hip_runtime.h>
#include <stdint.h>
#include <stddef.h>

// ---------- types ----------
typedef _Float16 half_t;
typedef half_t half8  __attribute__((ext_vector_type(8)));
typedef half_t half4v __attribute__((ext_vector_type(4)));
typedef float  f32x4  __attribute__((ext_vector_type(4)));

__device__ __forceinline__ float fast_sigmoid(float x) {
    float e = __builtin_amdgcn_exp2f(-1.44269504f * x);
    return __builtin_amdgcn_rcpf(1.0f + e);
}
__device__ __forceinline__ float fast_tanh(float x) {
    float e = __builtin_amdgcn_exp2f(2.88539008f * x);
    return 1.0f - 2.0f * __builtin_amdgcn_rcpf(1.0f + e);
}

// ---------------------------------------------------------------------------
// Prep: W [1024][256] f32 row-major -> MFMA-B fragment order, f16.
// Bijection (contiguous k): lane l, elem e of tile (T,kt) holds
//   B[k = kt*32 + (l>>4)*8 + e, j = T*16 + (l&15)].
// A-fragments from LDS use the SAME (lane-group,elem)->k mapping (validated
// R1/R3/R4/R5/R6: absmax 2e-3).
// ---------------------------------------------------------------------------
__global__ __launch_bounds__(64) void shuffle_w_kernel(
    const float* __restrict__ W, half_t* __restrict__ out)
{
    const int blk = blockIdx.x;         // 512 = 64 T * 8 kt
    const int T = blk >> 3, kt = blk & 7;
    const int l = threadIdx.x;
    const int j = T * 16 + (l & 15);
    const int k0 = kt * 32 + ((l >> 4) << 3);
    half8 v;
#pragma unroll
    for (int e = 0; e < 8; ++e) v[e] = (half_t)W[j * 256 + k0 + e];
    *reinterpret_cast<half8*>(out + (size_t)(blk * 64 + l) * 8) = v;
}

// ---------------------------------------------------------------------------
// Single-pass 4-gate GEMM: acc[mt*8 + g*2 + j] += hx(64x256) @ W^T tile
// (g*16 + w*2 + j).
// kt loop PINNED (unroll 1 + sched_barrier): caps the load-hoisting window.
// Evidence: R4/R5 (pinned, 64-reg budget) spilled ~12 slots; R6 (unpinned,
// 128-reg budget) spilled ~80 slots / 357 MB. Pinned live set here:
// cxr 32 + a 16 + B 32 + addr ~20 = ~100 arch < 128 budget; acc in AGPR.
// ---------------------------------------------------------------------------
__device__ __forceinline__ void gemm_all(
    f32x4* acc, const half_t* __restrict__ lhx,
    const half_t* __restrict__ Ws, int w, int lm, int lg, int l)
{
#pragma unroll 1
    for (int kt = 0; kt < 8; ++kt) {
        half8 a[4];
#pragma unroll
        for (int mt = 0; mt < 4; ++mt) {
            const int p = mt * 16 + lm;
            const int k = (kt * 32 + lg * 8) ^ ((p & 7) << 4);
            a[mt] = *reinterpret_cast<const half8*>(&lhx[p * 256 + k]);
        }
#pragma unroll
        for (int g = 0; g < 4; ++g)
#pragma unroll
            for (int j = 0; j < 2; ++j) {
                const int T = g * 16 + w * 2 + j;
                half8 b = *reinterpret_cast<const half8*>(
                    &Ws[(size_t)((T * 8 + kt) * 64 + l) * 8]);
#pragma unroll
                for (int mt = 0; mt < 4; ++mt)
                    acc[mt * 8 + g * 2 + j] = __builtin_amdgcn_mfma_f32_16x16x32_f16(
                        a[mt], b, acc[mt * 8 + g * 2 + j], 0, 0, 0);
            }
        __builtin_amdgcn_sched_barrier(0);   // no motion across kt iterations
    }
}

// ---------------------------------------------------------------------------
// Persistent LSTM: block = 64 rows x 16 steps, 8 waves (512 threads).
// Wave w owns h-cols [w*32, w*32+32) = tiles g*16 + w*2 + {0,1} per gate.
// ONE pass computes all 4 gates (acc = 32 f32x4 = 128 AGPR); epilogue is
// fully thread-local. 2 waves/SIMD, 256-unified-reg budget.
// LDS: hx 32 KB (XOR-swizzled rows) + x_proj frag dump 128 KB = 160 KB.
// ---------------------------------------------------------------------------
__global__ __launch_bounds__(512, 2) void lstm_kernel(
    const float* __restrict__ x,      // [8][256][1600]
    const float* __restrict__ hx0,    // [12800][256]
    const float* __restrict__ cx0,    // [12800][256]
    const float* __restrict__ b_ih,   // [1024]
    const float* __restrict__ b_hh,   // [1024]
    const float* __restrict__ W_lin,  // [2][256]
    const float* __restrict__ b_lin,  // [2]
    const half_t* __restrict__ Wih_s, // shuffled f16
    const half_t* __restrict__ Whh_s, // shuffled f16
    float* __restrict__ out)          // [12800][16][2]
{
    __shared__ __align__(16) half_t lds_hx[64 * 256];        // 32 KB
    __shared__ __align__(16) half_t lds_xp[8 * 32 * 64 * 4]; // 128 KB

    const int tid = threadIdx.x;
    const int w  = tid >> 6;   // wave 0..7
    const int l  = tid & 63;
    const int lm = l & 15;
    const int lg = l >> 4;

    const int row0 = blockIdx.x * 64;     // 200 blocks * 64 rows
    const int bb_  = row0 / 1600;
    const int p0   = row0 % 1600;

    // ---- stage x tile into lds_hx, f16 swizzled (coalesced on p) ----
    {
        const float* xin = x + (size_t)bb_ * 409600 + p0;   // x[b][c][p0+p]
        for (int it = 0; it < 32; ++it) {
            int idx = it * 512 + tid;
            int p = idx & 63, c = idx >> 6;
            lds_hx[p * 256 + (c ^ ((p & 7) << 4))] = (half_t)xin[c * 1600 + p];
        }
    }
    __syncthreads();

    f32x4 acc[32];

    // ---------------- phase 0: x_proj = x @ W_ih^T + b_ih + b_hh ----------
#pragma unroll
    for (int g = 0; g < 4; ++g)
#pragma unroll
        for (int j = 0; j < 2; ++j) {
            int col = g * 256 + (w * 2 + j) * 16 + lm;
            float bias = b_ih[col] + b_hh[col];
#pragma unroll
            for (int mt = 0; mt < 4; ++mt)
                acc[mt * 8 + g * 2 + j] = (f32x4){bias, bias, bias, bias};
        }
    gemm_all(acc, lds_hx, Wih_s, w, lm, lg, l);

    // dump x_proj to own-wave LDS region as f16 (read back identically)
#pragma unroll
    for (int f = 0; f < 32; ++f) {
        half4v xv;
#pragma unroll
        for (int r = 0; r < 4; ++r) xv[r] = (half_t)acc[f][r];
        *reinterpret_cast<half4v*>(&lds_xp[((w * 32 + f) * 64 + l) * 4]) = xv;
    }
    __syncthreads();   // x tile fully consumed, xp written

    // ---- stage h0 into lds_hx (coalesced on c); cx into registers ----
    {
        const float* hin = hx0 + (size_t)row0 * 256;
        for (int it = 0; it < 32; ++it) {
            int idx = it * 512 + tid;
            int c = idx & 255, p = idx >> 8;
            lds_hx[p * 256 + (c ^ ((p & 7) << 4))] = (half_t)hin[p * 256 + c];
        }
    }
    float cxr[32];
#pragma unroll
    for (int mt = 0; mt < 4; ++mt)
#pragma unroll
        for (int j = 0; j < 2; ++j)
#pragma unroll
            for (int r = 0; r < 4; ++r) {
                int p = mt * 16 + lg * 4 + r;
                int c = w * 32 + j * 16 + lm;
                cxr[(mt * 2 + j) * 4 + r] = cx0[(size_t)(row0 + p) * 256 + c];
            }
    __syncthreads();

    // ---------------- 16 recurrent steps ----------------
#pragma unroll 1
    for (int t = 0; t < 16; ++t) {
        // acc init = x_proj (own-wave frag dump)
#pragma unroll
        for (int f = 0; f < 32; ++f) {
            half4v u = *reinterpret_cast<const half4v*>(
                &lds_xp[((w * 32 + f) * 64 + l) * 4]);
#pragma unroll
            for (int r = 0; r < 4; ++r) acc[f][r] = (float)u[r];
        }

        gemm_all(acc, lds_hx, Whh_s, w, lm, lg, l);

        __syncthreads();   // all waves finished reading lds_hx(t)

        // cell update (all 4 gates local); write hx(t+1) f16-swizzled
#pragma unroll
        for (int mt = 0; mt < 4; ++mt)
#pragma unroll
            for (int j = 0; j < 2; ++j)
#pragma unroll
                for (int r = 0; r < 4; ++r) {
                    float iv = acc[mt * 8 + 0 + j][r];
                    float fv = acc[mt * 8 + 2 + j][r];
                    float gv = acc[mt * 8 + 4 + j][r];
                    float ov = acc[mt * 8 + 6 + j][r];
                    float cxn = fast_sigmoid(fv) * cxr[(mt * 2 + j) * 4 + r] +
                                fast_sigmoid(iv) * fast_tanh(gv);
                    cxr[(mt * 2 + j) * 4 + r] = cxn;
                    float h = fast_sigmoid(ov) * fast_tanh(cxn);
                    int p  = mt * 16 + lg * 4 + r;
                    int cc = w * 32 + j * 16 + lm;
                    lds_hx[p * 256 + (cc ^ ((p & 7) << 4))] = (half_t)h;
                }
        __syncthreads();   // hx(t+1) visible to all

        // head: y = leaky_relu(hx) @ W_lin^T + b_lin, write [n][t][o]
        {
            const int p = tid >> 3;          // row 0..63
            const int o = (tid >> 2) & 1;    // output 0..1
            const int q = tid & 3;           // quarter of the 256 h-cols
            const float* wl = W_lin + o * 256;
            float s = 0.0f;
#pragma unroll
            for (int cb = 0; cb < 16; ++cb) {
                int c0 = q * 64 + cb * 4;
                half4v u = *reinterpret_cast<const half4v*>(
                    &lds_hx[p * 256 + (c0 ^ ((p & 7) << 4))]);
                float4 wv = *reinterpret_cast<const float4*>(wl + c0);
                float h0 = (float)u[0], h1 = (float)u[1];
                float h2 = (float)u[2], h3 = (float)u[3];
                s += fmaxf(h0, 0.01f * h0) * wv.x;
                s += fmaxf(h1, 0.01f * h1) * wv.y;
                s += fmaxf(h2, 0.01f * h2) * wv.z;
                s += fmaxf(h3, 0.01f * h3) * wv.w;
            }
            s += __shfl_xor(s, 1);
            s += __shfl_xor(s, 2);
            if (q == 0)
                out[((size_t)(row0 + p) * 16 + t) * 2 + o] = s + b_lin[o];
        }
    }
}

// ---------------------------------------------------------------------------
extern "C" void kernel_launch(void* const* d_in, const int* in_sizes, int n_in,
                              void* d_out, int out_size, void* d_ws, size_t ws_size,
                              hipStream_t stream)
{
    const float* x    = (const float*)d_in[0];
    const float* hx   = (const float*)d_in[1];
    const float* cx   = (const float*)d_in[2];
    const float* Wih  = (const float*)d_in[3];
    const float* Whh  = (const float*)d_in[4];
    const float* bih  = (const float*)d_in[5];
    const float* bhh  = (const float*)d_in[6];
    const float* Wlin = (const float*)d_in[7];
    const float* blin = (const float*)d_in[8];
    float* out = (float*)d_out;

    half_t* wih_s = (half_t*)d_ws;             // 512 KB
    half_t* whh_s = wih_s + 1024 * 256;        // 512 KB

    shuffle_w_kernel<<<512, 64, 0, stream>>>(Wih, wih_s);
    shuffle_w_kernel<<<512, 64, 0, stream>>>(Whh, whh_s);
    lstm_kernel<<<200, 512, 0, stream>>>(x, hx, cx, bih, bhh, Wlin, blin,
                                         wih_s, whh_s, out);
}

// Round 8
// 356.044 us; speedup vs baseline: 2.1740x; 1.0172x over previous
//
#include <hip/hip_runtime.h>
#include <stdint.h>
#include <stddef.h>

// ---------- types ----------
typedef _Float16 half_t;
typedef half_t half8  __attribute__((ext_vector_type(8)));
typedef half_t half4v __attribute__((ext_vector_type(4)));
typedef float  f32x4  __attribute__((ext_vector_type(4)));

__device__ __forceinline__ float fast_sigmoid(float x) {
    float e = __builtin_amdgcn_exp2f(-1.44269504f * x);
    return __builtin_amdgcn_rcpf(1.0f + e);
}
__device__ __forceinline__ float fast_tanh(float x) {
    float e = __builtin_amdgcn_exp2f(2.88539008f * x);
    return 1.0f - 2.0f * __builtin_amdgcn_rcpf(1.0f + e);
}

// ---------------------------------------------------------------------------
// Prep: W [1024][256] f32 row-major -> MFMA-B fragment order, f16.
// Bijection (contiguous k): lane l, elem e of tile (T,kt) holds
//   B[k = kt*32 + (l>>4)*8 + e, j = T*16 + (l&15)].
// A-fragments from LDS use the SAME (lane-group,elem)->k mapping (validated
// R1-R7: absmax 2e-3).
// ---------------------------------------------------------------------------
__global__ __launch_bounds__(64) void shuffle_w_kernel(
    const float* __restrict__ W, half_t* __restrict__ out)
{
    const int blk = blockIdx.x;         // 512 = 64 T * 8 kt
    const int T = blk >> 3, kt = blk & 7;
    const int l = threadIdx.x;
    const int j = T * 16 + (l & 15);
    const int k0 = kt * 32 + ((l >> 4) << 3);
    half8 v;
#pragma unroll
    for (int e = 0; e < 8; ++e) v[e] = (half_t)W[j * 256 + k0 + e];
    *reinterpret_cast<half8*>(out + (size_t)(blk * 64 + l) * 8) = v;
}

// ---------------------------------------------------------------------------
// Single-pass 4-gate GEMM: acc[mt*8 + g*2 + j] += hx(64x256) @ W^T tile
// (g*16 + w*2 + j).
// kt loop PINNED (unroll 1 + sched_barrier): R4-R7 evidence says this caps
// in-loop hoisting (pinned ~12 spill slots vs unpinned ~80). R8 extends the
// same fencing to every phase seam (see lstm_kernel) to kill the rest.
// ---------------------------------------------------------------------------
__device__ __forceinline__ void gemm_all(
    f32x4* acc, const half_t* __restrict__ lhx,
    const half_t* __restrict__ Ws, int w, int lm, int lg, int l)
{
#pragma unroll 1
    for (int kt = 0; kt < 8; ++kt) {
        half8 a[4];
#pragma unroll
        for (int mt = 0; mt < 4; ++mt) {
            const int p = mt * 16 + lm;
            const int k = (kt * 32 + lg * 8) ^ ((p & 7) << 4);
            a[mt] = *reinterpret_cast<const half8*>(&lhx[p * 256 + k]);
        }
#pragma unroll
        for (int g = 0; g < 4; ++g)
#pragma unroll
            for (int j = 0; j < 2; ++j) {
                const int T = g * 16 + w * 2 + j;
                half8 b = *reinterpret_cast<const half8*>(
                    &Ws[(size_t)((T * 8 + kt) * 64 + l) * 8]);
#pragma unroll
                for (int mt = 0; mt < 4; ++mt)
                    acc[mt * 8 + g * 2 + j] = __builtin_amdgcn_mfma_f32_16x16x32_f16(
                        a[mt], b, acc[mt * 8 + g * 2 + j], 0, 0, 0);
            }
        __builtin_amdgcn_sched_barrier(0);   // no motion across kt iterations
    }
}

// ---------------------------------------------------------------------------
// Persistent LSTM: block = 64 rows x 16 steps, 8 waves (512 threads).
// Wave w owns h-cols [w*32, w*32+32) = tiles g*16 + w*2 + {0,1} per gate.
// ONE pass computes all 4 gates (acc = 32 f32x4 = 128 AGPR-side regs);
// epilogue fully thread-local. 2 waves/SIMD, 256-unified budget.
// R8: sched_barrier(0) at EVERY phase seam -- R7's remaining ~11-slot spill
// (93 MB writes) is cross-phase hoisting: kt=0 B-loads above the 64-reg
// acc-init window, and next step's B-loads above the head (global loads can
// cross s_barrier; LDS ops cannot).
// LDS: hx 32 KB (XOR-swizzled rows) + x_proj frag dump 128 KB = 160 KB.
// ---------------------------------------------------------------------------
__global__ __launch_bounds__(512, 2) void lstm_kernel(
    const float* __restrict__ x,      // [8][256][1600]
    const float* __restrict__ hx0,    // [12800][256]
    const float* __restrict__ cx0,    // [12800][256]
    const float* __restrict__ b_ih,   // [1024]
    const float* __restrict__ b_hh,   // [1024]
    const float* __restrict__ W_lin,  // [2][256]
    const float* __restrict__ b_lin,  // [2]
    const half_t* __restrict__ Wih_s, // shuffled f16
    const half_t* __restrict__ Whh_s, // shuffled f16
    float* __restrict__ out)          // [12800][16][2]
{
    __shared__ __align__(16) half_t lds_hx[64 * 256];        // 32 KB
    __shared__ __align__(16) half_t lds_xp[8 * 32 * 64 * 4]; // 128 KB

    const int tid = threadIdx.x;
    const int w  = tid >> 6;   // wave 0..7
    const int l  = tid & 63;
    const int lm = l & 15;
    const int lg = l >> 4;

    const int row0 = blockIdx.x * 64;     // 200 blocks * 64 rows
    const int bb_  = row0 / 1600;
    const int p0   = row0 % 1600;

    // ---- stage x tile into lds_hx, f16 swizzled (coalesced on p) ----
    {
        const float* xin = x + (size_t)bb_ * 409600 + p0;   // x[b][c][p0+p]
        for (int it = 0; it < 32; ++it) {
            int idx = it * 512 + tid;
            int p = idx & 63, c = idx >> 6;
            lds_hx[p * 256 + (c ^ ((p & 7) << 4))] = (half_t)xin[c * 1600 + p];
        }
    }
    __syncthreads();
    __builtin_amdgcn_sched_barrier(0);

    f32x4 acc[32];

    // ---------------- phase 0: x_proj = x @ W_ih^T + b_ih + b_hh ----------
#pragma unroll
    for (int g = 0; g < 4; ++g)
#pragma unroll
        for (int j = 0; j < 2; ++j) {
            int col = g * 256 + (w * 2 + j) * 16 + lm;
            float bias = b_ih[col] + b_hh[col];
#pragma unroll
            for (int mt = 0; mt < 4; ++mt)
                acc[mt * 8 + g * 2 + j] = (f32x4){bias, bias, bias, bias};
        }
    __builtin_amdgcn_sched_barrier(0);
    gemm_all(acc, lds_hx, Wih_s, w, lm, lg, l);

    // dump x_proj to own-wave LDS region as f16 (read back identically)
#pragma unroll
    for (int f = 0; f < 32; ++f) {
        half4v xv;
#pragma unroll
        for (int r = 0; r < 4; ++r) xv[r] = (half_t)acc[f][r];
        *reinterpret_cast<half4v*>(&lds_xp[((w * 32 + f) * 64 + l) * 4]) = xv;
    }
    __builtin_amdgcn_sched_barrier(0);
    __syncthreads();   // x tile fully consumed, xp written

    // ---- stage h0 into lds_hx (coalesced on c); cx into registers ----
    {
        const float* hin = hx0 + (size_t)row0 * 256;
        for (int it = 0; it < 32; ++it) {
            int idx = it * 512 + tid;
            int c = idx & 255, p = idx >> 8;
            lds_hx[p * 256 + (c ^ ((p & 7) << 4))] = (half_t)hin[p * 256 + c];
        }
    }
    float cxr[32];
#pragma unroll
    for (int mt = 0; mt < 4; ++mt)
#pragma unroll
        for (int j = 0; j < 2; ++j)
#pragma unroll
            for (int r = 0; r < 4; ++r) {
                int p = mt * 16 + lg * 4 + r;
                int c = w * 32 + j * 16 + lm;
                cxr[(mt * 2 + j) * 4 + r] = cx0[(size_t)(row0 + p) * 256 + c];
            }
    __syncthreads();
    __builtin_amdgcn_sched_barrier(0);

    // ---------------- 16 recurrent steps ----------------
#pragma unroll 1
    for (int t = 0; t < 16; ++t) {
        // phase 1: acc init = x_proj (own-wave frag dump)
#pragma unroll
        for (int f = 0; f < 32; ++f) {
            half4v u = *reinterpret_cast<const half4v*>(
                &lds_xp[((w * 32 + f) * 64 + l) * 4]);
#pragma unroll
            for (int r = 0; r < 4; ++r) acc[f][r] = (float)u[r];
        }
        __builtin_amdgcn_sched_barrier(0);   // seam: no kt=0 B-load hoist

        // phase 2: GEMM (kt-pinned inside)
        gemm_all(acc, lds_hx, Whh_s, w, lm, lg, l);

        __syncthreads();   // all waves finished reading lds_hx(t)

        // phase 3: cell update (4 gates local); write hx(t+1) f16-swizzled
#pragma unroll
        for (int mt = 0; mt < 4; ++mt)
#pragma unroll
            for (int j = 0; j < 2; ++j)
#pragma unroll
                for (int r = 0; r < 4; ++r) {
                    float iv = acc[mt * 8 + 0 + j][r];
                    float fv = acc[mt * 8 + 2 + j][r];
                    float gv = acc[mt * 8 + 4 + j][r];
                    float ov = acc[mt * 8 + 6 + j][r];
                    float cxn = fast_sigmoid(fv) * cxr[(mt * 2 + j) * 4 + r] +
                                fast_sigmoid(iv) * fast_tanh(gv);
                    cxr[(mt * 2 + j) * 4 + r] = cxn;
                    float h = fast_sigmoid(ov) * fast_tanh(cxn);
                    int p  = mt * 16 + lg * 4 + r;
                    int cc = w * 32 + j * 16 + lm;
                    lds_hx[p * 256 + (cc ^ ((p & 7) << 4))] = (half_t)h;
                }
        __builtin_amdgcn_sched_barrier(0);   // seam: epilogue self-contained
        __syncthreads();   // hx(t+1) visible to all

        // phase 4: head y = leaky_relu(hx) @ W_lin^T + b_lin -> [n][t][o]
        {
            const int p = tid >> 3;          // row 0..63
            const int o = (tid >> 2) & 1;    // output 0..1
            const int q = tid & 3;           // quarter of the 256 h-cols
            const float* wl = W_lin + o * 256;
            float s = 0.0f;
#pragma unroll
            for (int cb = 0; cb < 16; ++cb) {
                int c0 = q * 64 + cb * 4;
                half4v u = *reinterpret_cast<const half4v*>(
                    &lds_hx[p * 256 + (c0 ^ ((p & 7) << 4))]);
                float4 wv = *reinterpret_cast<const float4*>(wl + c0);
                float h0 = (float)u[0], h1 = (float)u[1];
                float h2 = (float)u[2], h3 = (float)u[3];
                s += fmaxf(h0, 0.01f * h0) * wv.x;
                s += fmaxf(h1, 0.01f * h1) * wv.y;
                s += fmaxf(h2, 0.01f * h2) * wv.z;
                s += fmaxf(h3, 0.01f * h3) * wv.w;
            }
            s += __shfl_xor(s, 1);
            s += __shfl_xor(s, 2);
            if (q == 0)
                out[((size_t)(row0 + p) * 16 + t) * 2 + o] = s + b_lin[o];
        }
        __builtin_amdgcn_sched_barrier(0);   // seam: no next-step hoist
    }
}

// ---------------------------------------------------------------------------
extern "C" void kernel_launch(void* const* d_in, const int* in_sizes, int n_in,
                              void* d_out, int out_size, void* d_ws, size_t ws_size,
                              hipStream_t stream)
{
    const float* x    = (const float*)d_in[0];
    const float* hx   = (const float*)d_in[1];
    const float* cx   = (const float*)d_in[2];
    const float* Wih  = (const float*)d_in[3];
    const float* Whh  = (const float*)d_in[4];
    const float* bih  = (const float*)d_in[5];
    const float* bhh  = (const float*)d_in[6];
    const float* Wlin = (const float*)d_in[7];
    const float* blin = (const float*)d_in[8];
    float* out = (float*)d_out;

    half_t* wih_s = (half_t*)d_ws;             // 512 KB
    half_t* whh_s = wih_s + 1024 * 256;        // 512 KB

    shuffle_w_kernel<<<512, 64, 0, stream>>>(Wih, wih_s);
    shuffle_w_kernel<<<512, 64, 0, stream>>>(Whh, whh_s);
    lstm_kernel<<<200, 512, 0, stream>>>(x, hx, cx, bih, bhh, Wlin, blin,
                                         wih_s, whh_s, out);
}